// Round 1
// 1761.634 us; speedup vs baseline: 1.6189x; 1.6189x over previous
//
#include <hip/hip_runtime.h>

#define S_ROWS 16384
#define T_ROWS 32768
#define NROWS  49152
#define DDIM   4096
#define C      21
#define KSPLIT 4

// workspace layout (in floats)
#define WT_OFF 0
#define WT_SZ  (C * DDIM)              // 86016: W transposed to [C][D]
#define P_OFF  (WT_OFF + WT_SZ)
#define P_SLOT (NROWS * C)             // 1032192 per k-slot
#define DM_OFF (P_OFF + KSPLIT * P_SLOT)
#define N_OFF  (DM_OFF + C)
#define NW_OFF (N_OFF + C)

// ---------------- kernel 1: transpose W, zero accumulators ----------------
__global__ void k_prep(const float* __restrict__ W, float* __restrict__ ws) {
    int idx = blockIdx.x * 256 + threadIdx.x;
    if (idx < C * DDIM) {
        int c = idx / DDIM, d = idx - c * DDIM;
        ws[WT_OFF + idx] = W[d * C + c];
    }
    if (blockIdx.x == 0 && threadIdx.x < 2 * C) {
        ws[DM_OFF + threadIdx.x] = 0.0f;   // zeroes delta_margin[21] + num[21]
    }
}

// ---------------- kernel 2: tiled GEMM partials -------------------------
// block: 256 threads = 4 waves; 256 rows/block; grid (192 row-groups, 4 k-chunks)
// wave w covers d-subrange [w*8, w*8+8) of each 32-wide k-tile; lane l owns rows
// l, l+64, l+128, l+192. acc[4][21] in registers; W tile broadcast from LDS.
//
// REGISTER-PRESSURE DISCIPLINE (the previous version spilled acc to scratch:
// VGPR_Count=84 == sizeof(acc), WRITE_SIZE=5.9GB of scratch thrash, VALUBusy 3.6%):
//  - the 8-wide d-slice is processed as two sequential 4-wide passes
//    (#pragma unroll 1) so only xr[4] + one W float4 are live alongside acc.
//  - acc indices are always compile-time constants (r,c loops fully unrolled;
//    only LDS byte addresses depend on the dynamic dd).
__launch_bounds__(256, 3)
__global__ void k_gemm(const float* __restrict__ src, const float* __restrict__ tgt,
                       float* __restrict__ ws) {
    __shared__ float smem[10752];           // 43008 B: stage (9888 fl) / red (10752 fl)
    const int tid = threadIdx.x;
    const int g   = blockIdx.x;             // row group (256 rows)
    const int ks  = blockIdx.y;             // k chunk (1024 d)
    const int l   = tid & 63, w = tid >> 6;
    const int w8  = w * 8;
    const int rg0 = g * 256;
    const float* xb = (rg0 < S_ROWS) ? (src + (size_t)rg0 * DDIM)
                                     : (tgt + (size_t)(rg0 - S_ROWS) * DDIM);
    const float* wt = ws + WT_OFF;

    float acc[4][C];
#pragma unroll
    for (int r = 0; r < 4; ++r)
#pragma unroll
        for (int c = 0; c < C; ++c) acc[r][c] = 0.0f;

    for (int t = 0; t < 32; ++t) {
        const int kb = ks * 1024 + t * 32;
        // stage X tile: 256 rows x 32 floats (stride 36 to break bank conflicts)
#pragma unroll
        for (int it = 0; it < 8; ++it) {
            int f = it * 256 + tid;
            int row = f >> 3, j4 = (f & 7) << 2;
            *(float4*)&smem[row * 36 + j4] =
                *(const float4*)(xb + (size_t)row * DDIM + kb + j4);
        }
        // stage Wt tile: 21 x 32
        if (tid < 168) {
            int c = tid >> 3, j4 = (tid & 7) << 2;
            *(float4*)&smem[9216 + c * 32 + j4] =
                *(const float4*)(wt + (size_t)c * DDIM + kb + j4);
        }
        __syncthreads();

        // two sequential 4-wide passes over this wave's 8-wide d-slice
#pragma unroll 1
        for (int dd = 0; dd < 8; dd += 4) {
            float4 xr[4];
#pragma unroll
            for (int r = 0; r < 4; ++r)
                xr[r] = *(const float4*)&smem[(l + r * 64) * 36 + w8 + dd];
#pragma unroll
            for (int c = 0; c < C; ++c) {
                float4 wv = *(const float4*)&smem[9216 + c * 32 + w8 + dd];
#pragma unroll
                for (int r = 0; r < 4; ++r) {
                    acc[r][c] += xr[r].x * wv.x + xr[r].y * wv.y +
                                 xr[r].z * wv.z + xr[r].w * wv.w;
                }
            }
        }
        __syncthreads();
    }

    // cross-wave reduction (two halves of 128 rows to fit LDS), store partials
    float* pout = ws + P_OFF + (size_t)ks * P_SLOT;
#pragma unroll
    for (int h = 0; h < 2; ++h) {
#pragma unroll
        for (int c = 0; c < C; ++c) {
            smem[w * 2688 + l * 21 + c]        = acc[2 * h][c];
            smem[w * 2688 + (l + 64) * 21 + c] = acc[2 * h + 1][c];
        }
        __syncthreads();
        for (int idx = tid; idx < 2688; idx += 256) {
            int row = idx / 21, c = idx - row * 21;
            float s = smem[row * 21 + c] + smem[2688 + row * 21 + c] +
                      smem[5376 + row * 21 + c] + smem[8064 + row * 21 + c];
            pout[(size_t)(rg0 + h * 128 + row) * 21 + c] = s;
        }
        __syncthreads();
    }
}

// ---------------- kernel 3: sum partials, softmax, stats ----------------
__global__ void k_phaseB(const float* __restrict__ b_cls, float* __restrict__ ws,
                         float* __restrict__ out) {
    const int tid = threadIdx.x;
    const int row = blockIdx.x * 256 + tid;
    const float* P = ws + P_OFF;
    float lg[C];
#pragma unroll
    for (int c = 0; c < C; ++c) lg[c] = b_cls[c];
    for (int k = 0; k < KSPLIT; ++k) {
        const float* p = P + (size_t)k * P_SLOT + (size_t)row * C;
#pragma unroll
        for (int c = 0; c < C; ++c) lg[c] += p[c];
    }
    float m = lg[0];
#pragma unroll
    for (int c = 1; c < C; ++c) m = fmaxf(m, lg[c]);
    float e[C], s = 0.0f;
#pragma unroll
    for (int c = 0; c < C; ++c) { e[c] = __expf(lg[c] - m); s += e[c]; }
    float inv = 1.0f / s;

    if (row < S_ROWS) {                    // block-uniform branch (64 src blocks)
        float* o = out + (size_t)row * 22;
#pragma unroll
        for (int c = 0; c < C; ++c) o[c] = e[c] * inv;
    } else {
        __shared__ float s_dm[C], s_n[C];
        if (tid < C) { s_dm[tid] = 0.0f; s_n[tid] = 0.0f; }
        __syncthreads();
        float top = -1.0f, sum = 0.0f; int arg = 0;
#pragma unroll
        for (int c = 0; c < C; ++c) {
            float p = e[c] * inv; sum += p;
            if (p > top) { top = p; arg = c; }   // strict > keeps first argmax
        }
        float margin = top - (sum - top) * (1.0f / (C - 1));
        if (arg != 0) {
            atomicAdd(&s_dm[arg], margin);
            atomicAdd(&s_n[arg], 1.0f);
        }
        __syncthreads();
        if (tid < C) {
            atomicAdd(&ws[DM_OFF + tid], s_dm[tid]);
            atomicAdd(&ws[N_OFF + tid], s_n[tid]);
        }
    }
}

// ---------------- kernel 4: blend + minmax normalize (1 block) ----------
__global__ void k_final(const float* __restrict__ tmf, const float* __restrict__ rec,
                        float* __restrict__ ws) {
    __shared__ float wv[C];
    __shared__ float mm[2];
    const int t = threadIdx.x;
    if (t < C) {
        float r = rec[0];
        float n = ws[N_OFF + t];
        float blended = (tmf[t] * r + ws[DM_OFF + t] / (n + 1e-6f)) / (r + 1.0f);
        float sn = 0.0f;
        for (int c = 0; c < C; ++c) sn += ws[N_OFF + c];
        wv[t] = (sn > 0.0f) ? blended : tmf[t];
    }
    __syncthreads();
    if (t == 0) {
        float mn = wv[0], mx = wv[0];
        for (int c = 1; c < C; ++c) { mn = fminf(mn, wv[c]); mx = fmaxf(mx, wv[c]); }
        mm[0] = mn; mm[1] = mx;
    }
    __syncthreads();
    if (t < C) ws[NW_OFF + t] = (wv[t] - mm[0]) / (mm[1] - mm[0] + 1e-12f);
}

// ---------------- kernel 5: gather weight column ------------------------
__global__ void k_gather(const int* __restrict__ label, const float* __restrict__ ws,
                         float* __restrict__ out) {
    int s = blockIdx.x * 256 + threadIdx.x;
    out[(size_t)s * 22 + 21] = ws[NW_OFF + label[s]];
}

extern "C" void kernel_launch(void* const* d_in, const int* in_sizes, int n_in,
                              void* d_out, int out_size, void* d_ws, size_t ws_size,
                              hipStream_t stream) {
    const float* src   = (const float*)d_in[0];
    const float* tgt   = (const float*)d_in[1];
    const float* W     = (const float*)d_in[2];
    const float* b     = (const float*)d_in[3];
    const int*   label = (const int*)d_in[4];
    const float* tmf   = (const float*)d_in[5];
    const float* rec   = (const float*)d_in[6];
    float* out = (float*)d_out;
    float* ws  = (float*)d_ws;

    k_prep<<<(C * DDIM + 255) / 256, 256, 0, stream>>>(W, ws);
    k_gemm<<<dim3(192, KSPLIT), 256, 0, stream>>>(src, tgt, ws);
    k_phaseB<<<NROWS / 256, 256, 0, stream>>>(b, ws, out);
    k_final<<<1, 64, 0, stream>>>(tmf, rec, ws);
    k_gather<<<S_ROWS / 256, 256, 0, stream>>>(label, ws, out);
}

// Round 2
// 468.093 us; speedup vs baseline: 6.0926x; 3.7634x over previous
//
#include <hip/hip_runtime.h>

#define S_ROWS 16384
#define T_ROWS 32768
#define NROWS  49152
#define DDIM   4096
#define C      21
#define KSPLIT 4

// workspace layout (in floats)
#define WT_OFF 0
#define WT_SZ  (C * DDIM)              // 86016: W transposed to [C][D]
#define P_OFF  (WT_OFF + WT_SZ)
#define P_SLOT (NROWS * C)             // 1032192 per k-slot
#define DM_OFF (P_OFF + KSPLIT * P_SLOT)
#define N_OFF  (DM_OFF + C)
#define NW_OFF (N_OFF + C)

// ---------------- kernel 1: transpose W, zero accumulators ----------------
__global__ void k_prep(const float* __restrict__ W, float* __restrict__ ws) {
    int idx = blockIdx.x * 256 + threadIdx.x;
    if (idx < C * DDIM) {
        int c = idx / DDIM, d = idx - c * DDIM;
        ws[WT_OFF + idx] = W[d * C + c];
    }
    if (blockIdx.x == 0 && threadIdx.x < 2 * C) {
        ws[DM_OFF + threadIdx.x] = 0.0f;   // zeroes delta_margin[21] + num[21]
    }
}

// ---------------- kernel 2: tiled GEMM partials -------------------------
// block: 256 threads = 4 waves; 256 rows/block; grid (192 row-groups, 4 k-chunks)
// wave w covers d-subrange [w*8, w*8+8) of each 32-wide k-tile; lane l owns rows
// l, l+64, l+128, l+192. acc[4][21] in registers; W tile broadcast from LDS.
//
// REGISTER-PRESSURE DISCIPLINE:
//  - R0/R1 both spilled acc to scratch (VGPR_Count=84 == "everything but acc",
//    WRITE_SIZE ~4-6 GB of scratch RMW, VALUBusy <6%). Root cause: the
//    __launch_bounds__(256,3) cap of ~168 VGPRs is below peak pressure
//    (~84 acc + 32 staging in-flight + xr/wv + addresses + alignment pads).
//  - Fix: __launch_bounds__(256,2) -> 256-VGPR budget. 2 blocks/CU is enough:
//    84 independent accumulators give huge ILP; spill-free >> occupancy.
//  - 8-wide d-slice processed as two sequential 4-wide passes (#pragma unroll 1)
//    to keep peak pressure low; acc indices always compile-time constants.
__launch_bounds__(256, 2)
__global__ void k_gemm(const float* __restrict__ src, const float* __restrict__ tgt,
                       float* __restrict__ ws) {
    __shared__ float smem[10752];           // 43008 B: stage (9888 fl) / red (10752 fl)
    const int tid = threadIdx.x;
    const int g   = blockIdx.x;             // row group (256 rows)
    const int ks  = blockIdx.y;             // k chunk (1024 d)
    const int l   = tid & 63, w = tid >> 6;
    const int w8  = w * 8;
    const int rg0 = g * 256;
    const float* xb = (rg0 < S_ROWS) ? (src + (size_t)rg0 * DDIM)
                                     : (tgt + (size_t)(rg0 - S_ROWS) * DDIM);
    const float* wt = ws + WT_OFF;

    float acc[4][C];
#pragma unroll
    for (int r = 0; r < 4; ++r)
#pragma unroll
        for (int c = 0; c < C; ++c) acc[r][c] = 0.0f;

    for (int t = 0; t < 32; ++t) {
        const int kb = ks * 1024 + t * 32;
        // stage X tile: 256 rows x 32 floats (stride 36 to break bank conflicts)
#pragma unroll
        for (int it = 0; it < 8; ++it) {
            int f = it * 256 + tid;
            int row = f >> 3, j4 = (f & 7) << 2;
            *(float4*)&smem[row * 36 + j4] =
                *(const float4*)(xb + (size_t)row * DDIM + kb + j4);
        }
        // stage Wt tile: 21 x 32
        if (tid < 168) {
            int c = tid >> 3, j4 = (tid & 7) << 2;
            *(float4*)&smem[9216 + c * 32 + j4] =
                *(const float4*)(wt + (size_t)c * DDIM + kb + j4);
        }
        __syncthreads();

        // two sequential 4-wide passes over this wave's 8-wide d-slice
#pragma unroll 1
        for (int dd = 0; dd < 8; dd += 4) {
            float4 xr[4];
#pragma unroll
            for (int r = 0; r < 4; ++r)
                xr[r] = *(const float4*)&smem[(l + r * 64) * 36 + w8 + dd];
#pragma unroll
            for (int c = 0; c < C; ++c) {
                float4 wv = *(const float4*)&smem[9216 + c * 32 + w8 + dd];
#pragma unroll
                for (int r = 0; r < 4; ++r) {
                    acc[r][c] += xr[r].x * wv.x + xr[r].y * wv.y +
                                 xr[r].z * wv.z + xr[r].w * wv.w;
                }
            }
        }
        __syncthreads();
    }

    // cross-wave reduction (two halves of 128 rows to fit LDS), store partials
    float* pout = ws + P_OFF + (size_t)ks * P_SLOT;
#pragma unroll
    for (int h = 0; h < 2; ++h) {
#pragma unroll
        for (int c = 0; c < C; ++c) {
            smem[w * 2688 + l * 21 + c]        = acc[2 * h][c];
            smem[w * 2688 + (l + 64) * 21 + c] = acc[2 * h + 1][c];
        }
        __syncthreads();
        for (int idx = tid; idx < 2688; idx += 256) {
            int row = idx / 21, c = idx - row * 21;
            float s = smem[row * 21 + c] + smem[2688 + row * 21 + c] +
                      smem[5376 + row * 21 + c] + smem[8064 + row * 21 + c];
            pout[(size_t)(rg0 + h * 128 + row) * 21 + c] = s;
        }
        __syncthreads();
    }
}

// ---------------- kernel 3: sum partials, softmax, stats ----------------
__global__ void k_phaseB(const float* __restrict__ b_cls, float* __restrict__ ws,
                         float* __restrict__ out) {
    const int tid = threadIdx.x;
    const int row = blockIdx.x * 256 + tid;
    const float* P = ws + P_OFF;
    float lg[C];
#pragma unroll
    for (int c = 0; c < C; ++c) lg[c] = b_cls[c];
    for (int k = 0; k < KSPLIT; ++k) {
        const float* p = P + (size_t)k * P_SLOT + (size_t)row * C;
#pragma unroll
        for (int c = 0; c < C; ++c) lg[c] += p[c];
    }
    float m = lg[0];
#pragma unroll
    for (int c = 1; c < C; ++c) m = fmaxf(m, lg[c]);
    float e[C], s = 0.0f;
#pragma unroll
    for (int c = 0; c < C; ++c) { e[c] = __expf(lg[c] - m); s += e[c]; }
    float inv = 1.0f / s;

    if (row < S_ROWS) {                    // block-uniform branch (64 src blocks)
        float* o = out + (size_t)row * 22;
#pragma unroll
        for (int c = 0; c < C; ++c) o[c] = e[c] * inv;
    } else {
        __shared__ float s_dm[C], s_n[C];
        if (tid < C) { s_dm[tid] = 0.0f; s_n[tid] = 0.0f; }
        __syncthreads();
        float top = -1.0f, sum = 0.0f; int arg = 0;
#pragma unroll
        for (int c = 0; c < C; ++c) {
            float p = e[c] * inv; sum += p;
            if (p > top) { top = p; arg = c; }   // strict > keeps first argmax
        }
        float margin = top - (sum - top) * (1.0f / (C - 1));
        if (arg != 0) {
            atomicAdd(&s_dm[arg], margin);
            atomicAdd(&s_n[arg], 1.0f);
        }
        __syncthreads();
        if (tid < C) {
            atomicAdd(&ws[DM_OFF + tid], s_dm[tid]);
            atomicAdd(&ws[N_OFF + tid], s_n[tid]);
        }
    }
}

// ---------------- kernel 4: blend + minmax normalize (1 block) ----------
__global__ void k_final(const float* __restrict__ tmf, const float* __restrict__ rec,
                        float* __restrict__ ws) {
    __shared__ float wv[C];
    __shared__ float mm[2];
    const int t = threadIdx.x;
    if (t < C) {
        float r = rec[0];
        float n = ws[N_OFF + t];
        float blended = (tmf[t] * r + ws[DM_OFF + t] / (n + 1e-6f)) / (r + 1.0f);
        float sn = 0.0f;
        for (int c = 0; c < C; ++c) sn += ws[N_OFF + c];
        wv[t] = (sn > 0.0f) ? blended : tmf[t];
    }
    __syncthreads();
    if (t == 0) {
        float mn = wv[0], mx = wv[0];
        for (int c = 1; c < C; ++c) { mn = fminf(mn, wv[c]); mx = fmaxf(mx, wv[c]); }
        mm[0] = mn; mm[1] = mx;
    }
    __syncthreads();
    if (t < C) ws[NW_OFF + t] = (wv[t] - mm[0]) / (mm[1] - mm[0] + 1e-12f);
}

// ---------------- kernel 5: gather weight column ------------------------
__global__ void k_gather(const int* __restrict__ label, const float* __restrict__ ws,
                         float* __restrict__ out) {
    int s = blockIdx.x * 256 + threadIdx.x;
    out[(size_t)s * 22 + 21] = ws[NW_OFF + label[s]];
}

extern "C" void kernel_launch(void* const* d_in, const int* in_sizes, int n_in,
                              void* d_out, int out_size, void* d_ws, size_t ws_size,
                              hipStream_t stream) {
    const float* src   = (const float*)d_in[0];
    const float* tgt   = (const float*)d_in[1];
    const float* W     = (const float*)d_in[2];
    const float* b     = (const float*)d_in[3];
    const int*   label = (const int*)d_in[4];
    const float* tmf   = (const float*)d_in[5];
    const float* rec   = (const float*)d_in[6];
    float* out = (float*)d_out;
    float* ws  = (float*)d_ws;

    k_prep<<<(C * DDIM + 255) / 256, 256, 0, stream>>>(W, ws);
    k_gemm<<<dim3(192, KSPLIT), 256, 0, stream>>>(src, tgt, ws);
    k_phaseB<<<NROWS / 256, 256, 0, stream>>>(b, ws, out);
    k_final<<<1, 64, 0, stream>>>(tmf, rec, ws);
    k_gather<<<S_ROWS / 256, 256, 0, stream>>>(label, ws, out);
}